// Round 9
// baseline (1196.866 us; speedup 1.0000x reference)
//
#include <hip/hip_runtime.h>

typedef __bf16 bf16_t;
typedef __attribute__((ext_vector_type(8))) __bf16 bf16x8;
typedef __attribute__((ext_vector_type(4))) float f32x4;
typedef unsigned short u16;
typedef unsigned int u32;
typedef unsigned long long u64;

#define TC 256
#define NCHUNK 4
#define LDA 264   // 256 + 8 bf16 pad
#define LOG2E 1.44269504f

// LDS-visibility-only barrier: leaves global prefetch loads (vmcnt) in flight.
#define LDS_BARRIER() asm volatile("s_waitcnt lgkmcnt(0)\n\ts_barrier" ::: "memory")

#if __has_builtin(__builtin_amdgcn_exp2f)
#define EXP2F __builtin_amdgcn_exp2f
#else
static __device__ __forceinline__ float EXP2F(float x) {
  float r;
  asm volatile("v_exp_f32 %0, %1\n\ts_nop 1" : "=v"(r) : "v"(x));
  return r;
}
#endif

// ws layout (bytes), total ~72.9 MB:
//   xg2  @ 0         : 64*256*2048*2 = 67,108,864  (bf16 xg chunk, scan-tiled,
//                       gates i,f,o pre-scaled by -log2e; gate c unscaled)
//   embb @ 67108864  : 10000*256*2   =  5,120,000
//   wkt  @ 72228864  : 512*256*2     =    262,144
//   hst  @ 72491008  : 64*4*128*4    =    131,072  (f32 h carry [g][p][u])
//   cst  @ 72622080  : 64*4*128*4    =    131,072  (f32 c carry)
//   wrt  @ 72753152  : 256*8*4*8*2  =    131,072  (bf16 Wr frags, scan-thread layout)
//
// xg2 layout (u16): off = ((g*256 + t)*2048) + tile*64 + c16*4 + row4
//   g = b>>2, row4 = b&3 (= p), tile = col>>4, c16 = col&15.
//   R9 scan lane (w,quad,l16), gate gj, sub s reads u16 at
//   (8gj+2w+s)*64 + l16*4 + quad  (dense 128-B block per wave per (gj,s)).

static __device__ __forceinline__ u16 bf16bits(float v) {
  return __builtin_bit_cast(u16, (bf16_t)v);
}
static __device__ __forceinline__ float bf16f(u16 v) {
  return __builtin_bit_cast(float, (u32)v << 16);
}

__global__ __launch_bounds__(256) void k_cvt_emb(const float* __restrict__ e,
                                                 u16* __restrict__ o, int n) {
  int i = blockIdx.x * 256 + threadIdx.x;
  if (i < n) o[i] = bf16bits(e[i]);
}

// WkT[n][k] = Wk[k][n]  (Wk is [256][512] row-major)
__global__ __launch_bounds__(256) void k_wkt(const float* __restrict__ wk,
                                             u16* __restrict__ o) {
  int i = blockIdx.x * 256 + threadIdx.x;  // 131072 total
  int k = i & 255, n = i >> 8;
  o[i] = bf16bits(wk[k * 512 + n]);
}

// Pre-bake Wr fragments in the scan's per-thread layout, gate-scaled:
// wrt[((tid*8 + jj)*4 + kt)*8 + e] = bf16(Wr[kt*32+quad*8+e][col] * sj)
// where jj = gj*2+s, col = 128*gj + 32*w + 16*s + l16, sj = (gj==2?1:-log2e).
__global__ __launch_bounds__(256) void k_wrt(const float* __restrict__ Wr,
                                             u16* __restrict__ o) {
  const int tid = threadIdx.x;
  const int w = tid >> 6, lane = tid & 63;
  const int l16 = lane & 15, quad = lane >> 4;
#pragma unroll
  for (int jj = 0; jj < 8; ++jj) {
    int gj = jj >> 1, s = jj & 1;
    float sj = (gj == 2) ? 1.0f : -LOG2E;
    int col = 128 * gj + 32 * w + 16 * s + l16;
#pragma unroll
    for (int kt = 0; kt < 4; ++kt)
#pragma unroll
      for (int e = 0; e < 8; ++e)
        o[((tid * 8 + jj) * 4 + kt) * 8 + e] =
            bf16bits(Wr[(kt * 32 + quad * 8 + e) * 512 + col] * sj);
  }
}

// xg2 = (emb[x] @ Wk + bias) * gate_scale, bf16, scan-tiled. (unchanged R8)
__global__ __launch_bounds__(512, 2) void k_xgemm(
    const int* __restrict__ x, const u16* __restrict__ embb,
    const u16* __restrict__ wkt, const float* __restrict__ bias,
    u16* __restrict__ xg, int t0) {
  __shared__ u16 Al[64 * LDA];
  __shared__ float biasl[512];
  const int tid = threadIdx.x;
  const int gg = blockIdx.x >> 6;
  const int tb = blockIdx.x & 63;
  const int w = tid >> 6, lane = tid & 63;
  const int l16 = lane & 15, quad = lane >> 4;

  bf16x8 bfr[4][8];
#pragma unroll
  for (int nt = 0; nt < 4; ++nt) {
    const u16* bp = wkt + (64 * w + 16 * nt + l16) * 256 + quad * 8;
#pragma unroll
    for (int kt = 0; kt < 8; ++kt)
      bfr[nt][kt] = *(const bf16x8*)(bp + kt * 32);
  }

#pragma unroll
  for (int p = 0; p < 4; ++p) {
    int f = p * 512 + tid;
    int lr = f >> 5, ch = f & 31;
    int xi = (16 * gg + (lr & 15)) * 1024 + t0 + tb * 4 + (lr >> 4);
    int idx = x[xi];
    *(uint4*)&Al[lr * LDA + ch * 8] = *(const uint4*)&embb[idx * 256 + ch * 8];
  }
  biasl[tid] = bias[tid];
  __syncthreads();

  f32x4 acc[4][4];
#pragma unroll
  for (int mt = 0; mt < 4; ++mt)
#pragma unroll
    for (int nt = 0; nt < 4; ++nt) acc[mt][nt] = f32x4{0.f, 0.f, 0.f, 0.f};

#pragma unroll
  for (int kt = 0; kt < 8; ++kt) {
    bf16x8 a[4];
#pragma unroll
    for (int mt = 0; mt < 4; ++mt)
      a[mt] = *(const bf16x8*)&Al[(mt * 16 + l16) * LDA + kt * 32 + quad * 8];
#pragma unroll
    for (int nt = 0; nt < 4; ++nt)
#pragma unroll
      for (int mt = 0; mt < 4; ++mt)
        acc[mt][nt] =
            __builtin_amdgcn_mfma_f32_16x16x32_bf16(a[mt], bfr[nt][kt], acc[mt][nt], 0, 0, 0);
  }

  const float gsc = ((w >> 1) == 2) ? 1.0f : -LOG2E;
  const size_t gtbase = ((size_t)(4 * gg + quad) * 256 + tb * 4) * 2048;
#pragma unroll
  for (int nt = 0; nt < 4; ++nt) {
    float bv = biasl[64 * w + 16 * nt + l16];
    int tile = 4 * w + nt;
#pragma unroll
    for (int mt = 0; mt < 4; ++mt) {
      u64 pk = 0;
#pragma unroll
      for (int r = 0; r < 4; ++r)
        pk |= (u64)bf16bits((acc[mt][nt][r] + bv) * gsc) << (16 * r);
      size_t off = gtbase + (size_t)mt * 2048 + tile * 64 + l16 * 4;
      *(u64*)&xg[off] = pk;
    }
  }
}

// MFMA scan R9: 64 wgs x 256 thr (4 waves, 1/SIMD). Wave w owns units
// 32w..32w+31, ALL 4 gates (8 n-tiles: (gj,s), col=128gj+32w+16s+l16).
// Each lane: batch row quad, units u0=32w+l16 and u1=u0+16; gates from
// acc[jj][0]. kt-chain split 2+2 (two accs + add) so 16 indep depth-2
// chains pipeline. Wr frags from pre-baked wrt (32 b128 loads).
__global__ __launch_bounds__(256, 1) void k_scan(
    const u16* __restrict__ xg, const u16* __restrict__ wrt,
    const float* __restrict__ Wd, const float* __restrict__ bd,
    float* __restrict__ hstf, float* __restrict__ cstf,
    float* __restrict__ out, int chunk) {
  const int g = blockIdx.x;
  const int tid = threadIdx.x;
  const int w = tid >> 6, lane = tid & 63;
  const int l16 = lane & 15, quad = lane >> 4;
  const int u0 = 32 * w + l16, u1 = u0 + 16;

  __shared__ __align__(16) u16 hbuf[2][4 * 144];
  __shared__ __align__(16) u16 zrow[128];

  // Wr fragments: wf[jj][kt] <- wrt (contiguous 512 B per thread)
  bf16x8 wf[8][4];
  {
    const u16* wp = wrt + tid * 256;
#pragma unroll
    for (int jj = 0; jj < 8; ++jj)
#pragma unroll
      for (int kt = 0; kt < 4; ++kt)
        wf[jj][kt] = *(const bf16x8*)(wp + (jj * 4 + kt) * 8);
  }

  if (tid < 128) zrow[tid] = 0;

  // carry: lane owns (row quad, units u0,u1)
  float c0 = 0.f, h0 = 0.f, c1v = 0.f, h1v = 0.f;
  if (chunk != 0) {
    c0 = cstf[(g * 4 + quad) * 128 + u0];
    h0 = hstf[(g * 4 + quad) * 128 + u0];
    c1v = cstf[(g * 4 + quad) * 128 + u1];
    h1v = hstf[(g * 4 + quad) * 128 + u1];
  }
  hbuf[0][quad * 144 + u0] = bf16bits(h0);
  hbuf[0][quad * 144 + u1] = bf16bits(h1v);

  // lane-constant LDS addresses
  const bool ald = (l16 & 3) == 0;
  const u16* rd0 = ald ? &hbuf[0][(l16 >> 2) * 144 + quad * 8] : &zrow[quad * 8];
  const u16* rd1 = ald ? &hbuf[1][(l16 >> 2) * 144 + quad * 8] : &zrow[quad * 8];
  u16* wr0 = &hbuf[0][quad * 144 + u0];
  u16* wr1 = &hbuf[1][quad * 144 + u0];

  // xg: gate (gj,s) = jj at xp[(jj>>1)*512 + (jj&1)*64]; +2048 per step
  const u16* xp = xg + (size_t)g * TC * 2048 + 2 * w * 64 + l16 * 4 + quad;
  u16 xq0[8], xq1[8];
#pragma unroll
  for (int jj = 0; jj < 8; ++jj)
    xq0[jj] = xp[(jj >> 1) * 512 + (jj & 1) * 64];
#pragma unroll
  for (int jj = 0; jj < 8; ++jj)
    xq1[jj] = xp[2048 + (jj >> 1) * 512 + (jj & 1) * 64];
  xp += 2 * 2048;

  __syncthreads();

  auto halfstep = [&](const u16* rd, u16* wr, u16* xv) {
    bf16x8 a[4];
#pragma unroll
    for (int kt = 0; kt < 4; ++kt)
      a[kt] = *(const bf16x8*)(rd + kt * 32);
    f32x4 accA[8], accB[8];
#pragma unroll
    for (int jj = 0; jj < 8; ++jj) {
      accA[jj] = f32x4{bf16f(xv[jj]), 0.f, 0.f, 0.f};  // C-seed = xg
      accB[jj] = f32x4{0.f, 0.f, 0.f, 0.f};
    }
#pragma unroll
    for (int jj = 0; jj < 8; ++jj) {
      accA[jj] = __builtin_amdgcn_mfma_f32_16x16x32_bf16(a[0], wf[jj][0], accA[jj], 0, 0, 0);
      accB[jj] = __builtin_amdgcn_mfma_f32_16x16x32_bf16(a[2], wf[jj][2], accB[jj], 0, 0, 0);
    }
#pragma unroll
    for (int jj = 0; jj < 8; ++jj) {
      accA[jj] = __builtin_amdgcn_mfma_f32_16x16x32_bf16(a[1], wf[jj][1], accA[jj], 0, 0, 0);
      accB[jj] = __builtin_amdgcn_mfma_f32_16x16x32_bf16(a[3], wf[jj][3], accB[jj], 0, 0, 0);
    }
    // re-prefetch (2 steps ahead; stays in flight across barrier)
#pragma unroll
    for (int jj = 0; jj < 8; ++jj)
      xv[jj] = xp[(jj >> 1) * 512 + (jj & 1) * 64];
    xp += 2048;
    // z[jj] = zi,zf,zc,zo for s=jj&1 (unit u0 if s==0 else u1)
    float z[8];
#pragma unroll
    for (int jj = 0; jj < 8; ++jj) z[jj] = accA[jj][0] + accB[jj][0];
    {
      float ig = __builtin_amdgcn_rcpf(1.f + EXP2F(z[0]));
      float fg = __builtin_amdgcn_rcpf(1.f + EXP2F(z[2]));
      float og = __builtin_amdgcn_rcpf(1.f + EXP2F(z[6]));
      float gg = fmaxf(z[4], 0.f);
      c0 = fg * c0 + ig * gg;
      h0 = og * fmaxf(c0, 0.f);
      wr[0] = bf16bits(h0);
    }
    {
      float ig = __builtin_amdgcn_rcpf(1.f + EXP2F(z[1]));
      float fg = __builtin_amdgcn_rcpf(1.f + EXP2F(z[3]));
      float og = __builtin_amdgcn_rcpf(1.f + EXP2F(z[7]));
      float gg = fmaxf(z[5], 0.f);
      c1v = fg * c1v + ig * gg;
      h1v = og * fmaxf(c1v, 0.f);
      wr[16] = bf16bits(h1v);
    }
    LDS_BARRIER();
  };

  for (int t2 = 0; t2 < TC; t2 += 2) {
    halfstep(rd0, wr1, xq0);  // even t: read buf0, write buf1
    halfstep(rd1, wr0, xq1);  // odd t:  read buf1, write buf0
  }

  if (chunk != NCHUNK - 1) {
    cstf[(g * 4 + quad) * 128 + u0] = c0;
    hstf[(g * 4 + quad) * 128 + u0] = h0;
    cstf[(g * 4 + quad) * 128 + u1] = c1v;
    hstf[(g * 4 + quad) * 128 + u1] = h1v;
  } else if (tid < 8) {
    // final h is in hbuf[0] (t=255 wrote buf 0; barrier passed)
    int p = tid >> 1, jo = tid & 1;
    float o = bd[jo];
    for (int k = 0; k < 128; ++k)
      o += bf16f(hbuf[0][p * 144 + k]) * Wd[k * 2 + jo];
    out[(g * 4 + p) * 2 + jo] = o;
  }
}

extern "C" void kernel_launch(void* const* d_in, const int* in_sizes, int n_in,
                              void* d_out, int out_size, void* d_ws, size_t ws_size,
                              hipStream_t stream) {
  const int* x = (const int*)d_in[0];
  const float* emb = (const float*)d_in[1];
  const float* Wk = (const float*)d_in[2];
  const float* Wr = (const float*)d_in[3];
  const float* bias = (const float*)d_in[4];
  const float* Wd = (const float*)d_in[5];
  const float* bd = (const float*)d_in[6];
  float* out = (float*)d_out;
  char* ws = (char*)d_ws;
  u16* xg = (u16*)(ws);
  u16* embb = (u16*)(ws + 67108864);
  u16* wkt = (u16*)(ws + 72228864);
  float* hst = (float*)(ws + 72491008);
  float* cst = (float*)(ws + 72622080);
  u16* wrt = (u16*)(ws + 72753152);

  k_cvt_emb<<<10000, 256, 0, stream>>>(emb, embb, 2560000);
  k_wkt<<<512, 256, 0, stream>>>(Wk, wkt);
  k_wrt<<<1, 256, 0, stream>>>(Wr, wrt);
  for (int chunk = 0; chunk < NCHUNK; ++chunk) {
    k_xgemm<<<1024, 512, 0, stream>>>(x, embb, wkt, bias, xg, chunk * TC);
    k_scan<<<64, 256, 0, stream>>>(xg, wrt, Wd, bd, hst, cst, out, chunk);
  }
}

// Round 10
// 758.138 us; speedup vs baseline: 1.5787x; 1.5787x over previous
//
#include <hip/hip_runtime.h>

typedef __bf16 bf16_t;
typedef __attribute__((ext_vector_type(8))) __bf16 bf16x8;
typedef __attribute__((ext_vector_type(4))) float f32x4;
typedef unsigned short u16;
typedef unsigned int u32;
typedef unsigned long long u64;

#define TC 256
#define NCHUNK 4
#define LDA 264   // 256 + 8 bf16 pad
#define LOG2E 1.44269504f

// LDS-visibility-only barrier: leaves global prefetch loads (vmcnt) in flight.
#define LDS_BARRIER() asm volatile("s_waitcnt lgkmcnt(0)\n\ts_barrier" ::: "memory")

#if __has_builtin(__builtin_amdgcn_exp2f)
#define EXP2F __builtin_amdgcn_exp2f
#else
static __device__ __forceinline__ float EXP2F(float x) {
  float r;
  asm volatile("v_exp_f32 %0, %1\n\ts_nop 1" : "=v"(r) : "v"(x));
  return r;
}
#endif

// ws layout (bytes), total ~72.8 MB:
//   xg2  @ 0         : 64*256*2048*2 = 67,108,864  (bf16 xg chunk, scan-tiled,
//                       gates i,f,o pre-scaled by -log2e; gate c unscaled)
//   embb @ 67108864  : 10000*256*2   =  5,120,000
//   wkt  @ 72228864  : 512*256*2     =    262,144
//   hst  @ 72491008  : 64*4*128*4    =    131,072  (f32 h carry [g][p][u])
//   cst  @ 72622080  : 64*4*128*4    =    131,072  (f32 c carry)
//
// xg2 layout (u16): off = ((g*256 + t)*2048) + tile*64 + c16*4 + row4
//   g = b>>2, row4 = b&3 (= p), tile = col>>4, c16 = col&15.
//   Scan lane (w,quad,l16) gate j reads u16 at (w+8j)*64 + l16*4 + quad.

static __device__ __forceinline__ u16 bf16bits(float v) {
  return __builtin_bit_cast(u16, (bf16_t)v);
}
static __device__ __forceinline__ float bf16f(u16 v) {
  return __builtin_bit_cast(float, (u32)v << 16);
}

__global__ __launch_bounds__(256) void k_cvt_emb(const float* __restrict__ e,
                                                 u16* __restrict__ o, int n) {
  int i = blockIdx.x * 256 + threadIdx.x;
  if (i < n) o[i] = bf16bits(e[i]);
}

// WkT[n][k] = Wk[k][n]  (Wk is [256][512] row-major)
__global__ __launch_bounds__(256) void k_wkt(const float* __restrict__ wk,
                                             u16* __restrict__ o) {
  int i = blockIdx.x * 256 + threadIdx.x;  // 131072 total
  int k = i & 255, n = i >> 8;
  o[i] = bf16bits(wk[k * 512 + n]);
}

// xg2 = (emb[x] @ Wk + bias) * gate_scale, bf16, scan-tiled. (unchanged R8)
__global__ __launch_bounds__(512, 2) void k_xgemm(
    const int* __restrict__ x, const u16* __restrict__ embb,
    const u16* __restrict__ wkt, const float* __restrict__ bias,
    u16* __restrict__ xg, int t0) {
  __shared__ u16 Al[64 * LDA];
  __shared__ float biasl[512];
  const int tid = threadIdx.x;
  const int gg = blockIdx.x >> 6;
  const int tb = blockIdx.x & 63;
  const int w = tid >> 6, lane = tid & 63;
  const int l16 = lane & 15, quad = lane >> 4;

  bf16x8 bfr[4][8];
#pragma unroll
  for (int nt = 0; nt < 4; ++nt) {
    const u16* bp = wkt + (64 * w + 16 * nt + l16) * 256 + quad * 8;
#pragma unroll
    for (int kt = 0; kt < 8; ++kt)
      bfr[nt][kt] = *(const bf16x8*)(bp + kt * 32);
  }

#pragma unroll
  for (int p = 0; p < 4; ++p) {
    int f = p * 512 + tid;
    int lr = f >> 5, ch = f & 31;
    int xi = (16 * gg + (lr & 15)) * 1024 + t0 + tb * 4 + (lr >> 4);
    int idx = x[xi];
    *(uint4*)&Al[lr * LDA + ch * 8] = *(const uint4*)&embb[idx * 256 + ch * 8];
  }
  biasl[tid] = bias[tid];
  __syncthreads();

  f32x4 acc[4][4];
#pragma unroll
  for (int mt = 0; mt < 4; ++mt)
#pragma unroll
    for (int nt = 0; nt < 4; ++nt) acc[mt][nt] = f32x4{0.f, 0.f, 0.f, 0.f};

#pragma unroll
  for (int kt = 0; kt < 8; ++kt) {
    bf16x8 a[4];
#pragma unroll
    for (int mt = 0; mt < 4; ++mt)
      a[mt] = *(const bf16x8*)&Al[(mt * 16 + l16) * LDA + kt * 32 + quad * 8];
#pragma unroll
    for (int nt = 0; nt < 4; ++nt)
#pragma unroll
      for (int mt = 0; mt < 4; ++mt)
        acc[mt][nt] =
            __builtin_amdgcn_mfma_f32_16x16x32_bf16(a[mt], bfr[nt][kt], acc[mt][nt], 0, 0, 0);
  }

  const float gsc = ((w >> 1) == 2) ? 1.0f : -LOG2E;
  const size_t gtbase = ((size_t)(4 * gg + quad) * 256 + tb * 4) * 2048;
#pragma unroll
  for (int nt = 0; nt < 4; ++nt) {
    float bv = biasl[64 * w + 16 * nt + l16];
    int tile = 4 * w + nt;
#pragma unroll
    for (int mt = 0; mt < 4; ++mt) {
      u64 pk = 0;
#pragma unroll
      for (int r = 0; r < 4; ++r)
        pk |= (u64)bf16bits((acc[mt][nt][r] + bv) * gsc) << (16 * r);
      size_t off = gtbase + (size_t)mt * 2048 + tile * 64 + l16 * 4;
      *(u64*)&xg[off] = pk;
    }
  }
}

// MFMA scan (R8 structure, 8 waves): 64 wgs x 512 thr; wg g owns batch rows
// 4g..4g+3 in M-slots {0,4,8,12}; every lane owns unit (row quad, col
// u=16w+l16), gates acc[0..3][0]. R10 change: K-accumulation split into two
// accumulators per gate (accA: kt0-1, accB: kt2-3), issued j-inner, so
// dependent MFMAs on one accumulator are 8 issue slots apart (kills the
// ~35-60 cyc/MFMA in-order dependency stalls that pinned R7-R8 at ~1210
// cyc/step; R9's wave-halving showed step scales with per-wave MFMA count).
__global__ __launch_bounds__(512) void k_scan(
    const u16* __restrict__ xg, const float* __restrict__ Wr,
    const float* __restrict__ Wd, const float* __restrict__ bd,
    float* __restrict__ hstf, float* __restrict__ cstf,
    float* __restrict__ out, int chunk) {
  const int g = blockIdx.x;
  const int tid = threadIdx.x;
  const int w = tid >> 6, lane = tid & 63;
  const int l16 = lane & 15, quad = lane >> 4;
  const int u = 16 * w + l16;

  __shared__ __align__(16) u16 hbuf[2][4 * 144];
  __shared__ __align__(16) u16 zrow[128];

  bf16x8 wf[4][4];
#pragma unroll
  for (int j = 0; j < 4; ++j) {
    const float sj = (j == 2) ? 1.0f : -LOG2E;
#pragma unroll
    for (int kt = 0; kt < 4; ++kt) {
      const float* p = Wr + (kt * 32 + quad * 8) * 512 + u + 128 * j;
#pragma unroll
      for (int jj = 0; jj < 8; ++jj) wf[j][kt][jj] = (bf16_t)(p[jj * 512] * sj);
    }
  }

  if (tid < 128) zrow[tid] = 0;

  float c1 = 0.f, h1 = 0.f;
  if (chunk != 0) {
    c1 = cstf[(g * 4 + quad) * 128 + u];
    h1 = hstf[(g * 4 + quad) * 128 + u];
  }
  hbuf[0][quad * 144 + u] = bf16bits(h1);

  const bool ald = (l16 & 3) == 0;
  const u16* rd0 = ald ? &hbuf[0][(l16 >> 2) * 144 + quad * 8] : &zrow[quad * 8];
  const u16* rd1 = ald ? &hbuf[1][(l16 >> 2) * 144 + quad * 8] : &zrow[quad * 8];
  u16* wr0 = &hbuf[0][quad * 144 + u];
  u16* wr1 = &hbuf[1][quad * 144 + u];

  const u16* xp = xg + (size_t)g * TC * 2048 + w * 64 + l16 * 4 + quad;
  u16 xq0[4], xq1[4];
#pragma unroll
  for (int j = 0; j < 4; ++j) xq0[j] = xp[j * 512];
#pragma unroll
  for (int j = 0; j < 4; ++j) xq1[j] = xp[2048 + j * 512];
  xp += 2 * 2048;

  __syncthreads();

  auto halfstep = [&](const u16* rd, u16* wr, u16* xv) {
    bf16x8 a[4];
#pragma unroll
    for (int kt = 0; kt < 4; ++kt)
      a[kt] = *(const bf16x8*)(rd + kt * 32);
    f32x4 accA[4], accB[4];
#pragma unroll
    for (int j = 0; j < 4; ++j) {
      accA[j] = f32x4{bf16f(xv[j]), 0.f, 0.f, 0.f};  // C-seed = xg
      accB[j] = f32x4{0.f, 0.f, 0.f, 0.f};
    }
    // j-inner issue order: dependent MFMAs on one accumulator are 8 apart
#pragma unroll
    for (int j = 0; j < 4; ++j)
      accA[j] = __builtin_amdgcn_mfma_f32_16x16x32_bf16(a[0], wf[j][0], accA[j], 0, 0, 0);
#pragma unroll
    for (int j = 0; j < 4; ++j)
      accB[j] = __builtin_amdgcn_mfma_f32_16x16x32_bf16(a[2], wf[j][2], accB[j], 0, 0, 0);
#pragma unroll
    for (int j = 0; j < 4; ++j)
      accA[j] = __builtin_amdgcn_mfma_f32_16x16x32_bf16(a[1], wf[j][1], accA[j], 0, 0, 0);
#pragma unroll
    for (int j = 0; j < 4; ++j)
      accB[j] = __builtin_amdgcn_mfma_f32_16x16x32_bf16(a[3], wf[j][3], accB[j], 0, 0, 0);
    // re-prefetch (2 steps ahead; stays in flight across barrier)
#pragma unroll
    for (int j = 0; j < 4; ++j) xv[j] = xp[j * 512];
    xp += 2048;
    float zi = accA[0][0] + accB[0][0];
    float zf = accA[1][0] + accB[1][0];
    float zc = accA[2][0] + accB[2][0];
    float zo = accA[3][0] + accB[3][0];
    float ig = __builtin_amdgcn_rcpf(1.f + EXP2F(zi));
    float fg = __builtin_amdgcn_rcpf(1.f + EXP2F(zf));
    float og = __builtin_amdgcn_rcpf(1.f + EXP2F(zo));
    float gg = fmaxf(zc, 0.f);
    c1 = fg * c1 + ig * gg;
    h1 = og * fmaxf(c1, 0.f);
    *wr = bf16bits(h1);
    LDS_BARRIER();
  };

  for (int t2 = 0; t2 < TC; t2 += 2) {
    halfstep(rd0, wr1, xq0);  // even t: read buf0, write buf1
    halfstep(rd1, wr0, xq1);  // odd t:  read buf1, write buf0
  }

  if (chunk != NCHUNK - 1) {
    cstf[(g * 4 + quad) * 128 + u] = c1;
    hstf[(g * 4 + quad) * 128 + u] = h1;
  } else if (tid < 8) {
    int p = tid >> 1, jo = tid & 1;
    float o = bd[jo];
    for (int k = 0; k < 128; ++k)
      o += bf16f(hbuf[0][p * 144 + k]) * Wd[k * 2 + jo];
    out[(g * 4 + p) * 2 + jo] = o;
  }
}

extern "C" void kernel_launch(void* const* d_in, const int* in_sizes, int n_in,
                              void* d_out, int out_size, void* d_ws, size_t ws_size,
                              hipStream_t stream) {
  const int* x = (const int*)d_in[0];
  const float* emb = (const float*)d_in[1];
  const float* Wk = (const float*)d_in[2];
  const float* Wr = (const float*)d_in[3];
  const float* bias = (const float*)d_in[4];
  const float* Wd = (const float*)d_in[5];
  const float* bd = (const float*)d_in[6];
  float* out = (float*)d_out;
  char* ws = (char*)d_ws;
  u16* xg = (u16*)(ws);
  u16* embb = (u16*)(ws + 67108864);
  u16* wkt = (u16*)(ws + 72228864);
  float* hst = (float*)(ws + 72491008);
  float* cst = (float*)(ws + 72622080);

  k_cvt_emb<<<10000, 256, 0, stream>>>(emb, embb, 2560000);
  k_wkt<<<512, 256, 0, stream>>>(Wk, wkt);
  for (int chunk = 0; chunk < NCHUNK; ++chunk) {
    k_xgemm<<<1024, 512, 0, stream>>>(x, embb, wkt, bias, xg, chunk * TC);
    k_scan<<<64, 512, 0, stream>>>(xg, Wr, Wd, bd, hst, cst, out, chunk);
  }
}